// Round 11
// baseline (191.647 us; speedup 1.0000x reference)
//
#include <hip/hip_runtime.h>
#include <math.h>

namespace {

constexpr int SOUT = 12;    // (14-3)/1+1
constexpr int OCAP = 32;
constexpr int PD   = 16;    // 4x4 pose
constexpr int NI   = 288;   // 3*3*32
constexpr int SUBS = 4;     // i-dimension split factor
constexpr int ISUB = NI / SUBS;        // 72 input caps per (block,sub)
constexpr int NPOS = 4 * SOUT * SOUT;  // 576 output positions
constexpr float EPSF = 1e-9f;
constexpr int CHUNK = 34 * 32;         // per-(n,sub) partial: [o][34]; j 0..15 S1, 16..31 S2, 32 S0
constexpr int SSTR  = 36;              // stat row stride per o: 16 i2, 16 ng, bias, pad
constexpr size_t POSE_OUT = (size_t)NPOS * OCAP * PD;  // 294912

typedef float v2f __attribute__((ext_vector_type(2)));

__device__ __forceinline__ v2f vfma(v2f a, v2f b, v2f c) { return __builtin_elementwise_fma(a, b, c); }
__device__ __forceinline__ v2f splat(float a) { v2f r; r.x = a; r.y = a; return r; }

// DPP lane exchange (compile-time ctrl); folds into v_max_f32_dpp / v_add_f32_dpp.
template<int CTRL>
__device__ __forceinline__ float dppf(float x) {
    return __int_as_float(__builtin_amdgcn_update_dpp(0, __float_as_int(x), CTRL, 0xF, 0xF, true));
}
// ds_swizzle xor-16 within 32-lane groups (BitMode: offset = (xor<<10) | and=0x1F)
#define SWZ16(x) __int_as_float(__builtin_amdgcn_ds_swizzle(__float_as_int(x), (16 << 10) | 0x1F))

// 32-lane all-reduce (progressive-uniformity butterfly, verified R8-R10)
__device__ __forceinline__ float redmax32(float x) {
    x = fmaxf(x, dppf<0xB1>(x));    // quad_perm xor1
    x = fmaxf(x, dppf<0x4E>(x));    // quad_perm xor2
    x = fmaxf(x, dppf<0x141>(x));   // row_half_mirror
    x = fmaxf(x, dppf<0x140>(x));   // row_mirror
    x = fmaxf(x, SWZ16(x));
    return x;
}
__device__ __forceinline__ float redsum32(float x) {
    x += dppf<0xB1>(x);
    x += dppf<0x4E>(x);
    x += dppf<0x141>(x);
    x += dppf<0x140>(x);
    x += SWZ16(x);
    return x;
}

// ---------------------------------------------------------------------------
// Sweep: block = (yx, sub). 4 waves; wave = batch b (W stream shared via L1).
// Lane = (o = lane&31, rh = lane>>5). One i per wave-step: lane holds vote
// dims d in {p*4+2rh, p*4+2rh+1} as v2f v[p]. Softmax over o runs redundantly
// in both 32-lane halves after a single xor-32 ts fold. 18 iters x 4 i.
// ---------------------------------------------------------------------------
template<int SWEEP>
__global__ __launch_bounds__(256, 2)
void sweep_kernel(const float* __restrict__ pose_in,   // [4,14,14,32,16]
                  const float* __restrict__ act_in,    // [4,14,14,32]
                  const float* __restrict__ wmat,      // [288,32,16]
                  const float* __restrict__ statbuf,   // [576][32][36] finalized stats
                  float* __restrict__ outbuf)          // partials [n*4+sub][CHUNK]
{
    __shared__ __align__(16) float sP[4 * ISUB * PD]; // 18.4 KB: 4 batches' i-chunks
    __shared__ float sA[4 * ISUB];

    const int bid = blockIdx.x;
    const int yx  = bid >> 2;
    const int sub = bid & 3;
    const int y   = yx / SOUT;
    const int x   = yx % SOUT;

    const int t    = threadIdx.x;
    const int wave = t >> 6;            // 0..3 = batch b
    const int lane = t & 63;
    const int o    = lane & 31;
    const int rh   = lane >> 5;         // r-pair half: dims p*4+2rh, p*4+2rh+1

    // ---- stage 4 batches' i-chunks (coalesced float4) ----
    {
        const float4* src = reinterpret_cast<const float4*>(pose_in);
        float4* dst = reinterpret_cast<float4*>(sP);
        for (int u = t; u < 4 * ISUB * 4; u += 256) {  // 1152 float4
            const int bs   = u / (ISUB * 4);
            const int r    = u - bs * (ISUB * 4);
            const int il   = r >> 2;
            const int comp = r & 3;
            const int ig   = sub * ISUB + il;
            const int k = ig >> 5, c = ig & 31;
            const int ki = k / 3, kj = k - ki * 3;
            const int cell = (bs * 14 + y + ki) * 14 + (x + kj);
            dst[u] = src[(size_t)(cell * 32 + c) * 4 + comp];
        }
        for (int u = t; u < 4 * ISUB; u += 256) {
            const int bs = u / ISUB;
            const int il = u - bs * ISUB;
            const int ig = sub * ISUB + il;
            const int k = ig >> 5, c = ig & 31;
            const int ki = k / 3, kj = k - ki * 3;
            const int cell = (bs * 14 + y + ki) * 14 + (x + kj);
            sA[u] = act_in[(size_t)cell * 32 + c];
        }
    }

    const int n = wave * (SOUT * SOUT) + yx;

    // per-lane register cache of stats: only this lane's 8 dims (4 v2f pairs)
    float bias_r = 0.f;
    v2f i2r[4], ngr[4];
    if constexpr (SWEEP > 0) {
        const float* st = statbuf + ((size_t)n * OCAP + o) * SSTR;
        #pragma unroll
        for (int p = 0; p < 4; ++p) {
            i2r[p] = *reinterpret_cast<const v2f*>(st + p * 4 + 2 * rh);
            ngr[p] = *reinterpret_cast<const v2f*>(st + 16 + p * 4 + 2 * rh);
        }
        bias_r = st[32];
    }
    __syncthreads();

    v2f s1[4], s2[4];
    float s0acc = 0.f;
    #pragma unroll
    for (int p = 0; p < 4; ++p) { s1[p] = splat(0.f); s2[p] = splat(0.f); }

    // lane W base: row (sub*72 + i)*32 + o, cols q*4 + 2rh; i stride = 512 floats
    const float* wl = wmat + ((size_t)(sub * ISUB) * OCAP + o) * PD + rh * 2;
    const float* pb = sP + wave * ISUB * PD;
    const float* ab = sA + wave * ISUB;

    #pragma unroll 1
    for (int it = 0; it < ISUB / 4; ++it) {     // 18 iterations, 4 i each
        const int i0 = it * 4;

        // front-load all 4 i's W fragments (16 dwordx2) + activations
        v2f W[4][4];
        float av[4];
        #pragma unroll
        for (int ii = 0; ii < 4; ++ii) {
            const float* wi = wl + (size_t)(i0 + ii) * 512;
            #pragma unroll
            for (int q = 0; q < 4; ++q)
                W[ii][q] = *reinterpret_cast<const v2f*>(wi + q * 4);
            av[ii] = ab[i0 + ii];
        }

        // 4 independent vote+softmax+accumulate chains
        #pragma unroll
        for (int ii = 0; ii < 4; ++ii) {
            const float* pr = pb + (i0 + ii) * PD;
            const float4 p0 = *reinterpret_cast<const float4*>(pr);
            const float4 p1 = *reinterpret_cast<const float4*>(pr + 4);
            const float4 p2 = *reinterpret_cast<const float4*>(pr + 8);
            const float4 p3 = *reinterpret_cast<const float4*>(pr + 12);

            v2f v[4];
            v[0] = vfma(splat(p0.x), W[ii][0], vfma(splat(p0.y), W[ii][1],
                   vfma(splat(p0.z), W[ii][2], splat(p0.w) * W[ii][3])));
            v[1] = vfma(splat(p1.x), W[ii][0], vfma(splat(p1.y), W[ii][1],
                   vfma(splat(p1.z), W[ii][2], splat(p1.w) * W[ii][3])));
            v[2] = vfma(splat(p2.x), W[ii][0], vfma(splat(p2.y), W[ii][1],
                   vfma(splat(p2.z), W[ii][2], splat(p2.w) * W[ii][3])));
            v[3] = vfma(splat(p3.x), W[ii][0], vfma(splat(p3.y), W[ii][1],
                   vfma(splat(p3.z), W[ii][2], splat(p3.w) * W[ii][3])));

            float rrp;
            if constexpr (SWEEP == 0) {
                rrp = av[ii] * (1.0f / 32.0f);
            } else {
                v2f ts2 = splat(0.f);
                #pragma unroll
                for (int p = 0; p < 4; ++p) {
                    const v2f tmp = vfma(v[p], i2r[p], ngr[p]);
                    ts2 = vfma(v[p], tmp, ts2);
                }
                float ts = ts2.x + ts2.y;
                ts += __shfl_xor(ts, 32, 64);          // fold the other 8 dims
                const float zz = bias_r - ts;
                const float m = redmax32(zz);
                const float e = __expf(zz - m);
                const float es = redsum32(e);
                rrp = __fdividef(e, es) * av[ii];
            }

            s0acc += rrp;
            const v2f rr2 = splat(rrp);
            #pragma unroll
            for (int p = 0; p < 4; ++p) {
                const v2f rv = rr2 * v[p];
                s1[p] = s1[p] + rv;
                s2[p] = vfma(rv, v[p], s2[p]);
            }
        }
    }

    // direct store: lane owns distinct (o, dim-pair) -> no cross-lane fold
    float* dstc = outbuf + (size_t)(n * SUBS + sub) * CHUNK + o * 34;
    #pragma unroll
    for (int p = 0; p < 4; ++p) {
        *reinterpret_cast<float2*>(dstc + p * 4 + 2 * rh)      = float2{s1[p].x, s1[p].y};
        *reinterpret_cast<float2*>(dstc + 16 + p * 4 + 2 * rh) = float2{s2[p].x, s2[p].y};
    }
    if (rh == 0) dstc[32] = s0acc;      // both halves hold identical s0
}

// ---------------------------------------------------------------------------
// Stats: finalize iteration stats from the 4 sub-chunks, once per n.
// ---------------------------------------------------------------------------
template<int IT>
__global__ __launch_bounds__(256, 4)
void stats_kernel(const float* __restrict__ prev,
                  const float* __restrict__ beta_v,
                  const float* __restrict__ beta_a,
                  float* __restrict__ statbuf)
{
    const int n  = blockIdx.x;
    const int t  = threadIdx.x;
    const int oo = t >> 3, dp = t & 7, d0 = dp * 2;
    const float* base = prev + (size_t)n * (SUBS * CHUNK) + oo * 34;
    float s0 = 0.f, S1a = 0.f, S1b = 0.f, S2a = 0.f, S2b = 0.f;
    #pragma unroll
    for (int s = 0; s < SUBS; ++s) {
        const float* c = base + s * CHUNK;
        s0  += c[32];
        S1a += c[d0];
        S1b += c[d0 + 1];
        S2a += c[16 + d0];
        S2b += c[17 + d0];
    }
    const float inv = 1.f / s0;
    const float m0 = S1a * inv, m1 = S1b * inv;
    const float v0 = fmaxf(fmaf(-m0, m0, S2a * inv), 0.f);
    const float v1 = fmaxf(fmaf(-m1, m1, S2b * inv), 0.f);
    const float i20 = 0.5f / fmaxf(v0, 1e-30f);
    const float i21 = 0.5f / fmaxf(v1, 1e-30f);
    float ll = __logf(sqrtf(v0) + EPSF) + __logf(sqrtf(v1) + EPSF);
    float c0 = m0 * m0 * i20 + m1 * m1 * i21;

    float* st = statbuf + ((size_t)n * OCAP + oo) * SSTR;
    st[d0]          = i20;
    st[d0 + 1]      = i21;
    st[16 + d0]     = -2.f * m0 * i20;
    st[17 + d0]     = -2.f * m1 * i21;

    #pragma unroll
    for (int m = 1; m <= 4; m <<= 1) {
        ll += __shfl_xor(ll, m, 8);
        c0 += __shfl_xor(c0, m, 8);
    }
    if (dp == 0) {
        const float cost = s0 * fmaf(16.f, beta_v[oo], ll);
        const float oact = 1.f / (1.f + __expf(-(float)IT * (beta_a[oo] - cost)));
        st[32] = __logf(oact + EPSF) - ll - c0;
    }
}

__global__ __launch_bounds__(256, 4)
void final_kernel(const float* __restrict__ prev,      // partials of sweep 2
                  const float* __restrict__ beta_v,
                  const float* __restrict__ beta_a,
                  float* __restrict__ out)
{
    const int n  = blockIdx.x;
    const int t  = threadIdx.x;
    const int oo = t >> 3, dp = t & 7, d0 = dp * 2;
    const float* base = prev + (size_t)n * (SUBS * CHUNK) + oo * 34;
    float s0 = 0.f, S1a = 0.f, S1b = 0.f, S2a = 0.f, S2b = 0.f;
    #pragma unroll
    for (int s = 0; s < SUBS; ++s) {
        const float* c = base + s * CHUNK;
        s0  += c[32];
        S1a += c[d0];
        S1b += c[d0 + 1];
        S2a += c[16 + d0];
        S2b += c[17 + d0];
    }
    const float inv = 1.f / s0;
    const float m0 = S1a * inv, m1 = S1b * inv;
    out[(size_t)n * (OCAP * PD) + oo * PD + d0]     = m0;
    out[(size_t)n * (OCAP * PD) + oo * PD + d0 + 1] = m1;

    const float v0 = fmaxf(fmaf(-m0, m0, S2a * inv), 0.f);
    const float v1 = fmaxf(fmaf(-m1, m1, S2b * inv), 0.f);
    float lt = __logf(sqrtf(v0) + EPSF) + __logf(sqrtf(v1) + EPSF);
    lt += __shfl_xor(lt, 1, 8);
    lt += __shfl_xor(lt, 2, 8);
    lt += __shfl_xor(lt, 4, 8);
    if (dp == 0) {
        const float cost = s0 * fmaf(16.f, beta_v[oo], lt);
        const float oact = 1.f / (1.f + __expf(-3.0f * (beta_a[oo] - cost)));  // inv_temp=3 at it=2
        out[POSE_OUT + (size_t)n * OCAP + oo] = oact;
    }
}

} // namespace

extern "C" void kernel_launch(void* const* d_in, const int* in_sizes, int n_in,
                              void* d_out, int out_size, void* d_ws, size_t ws_size,
                              hipStream_t stream) {
    const float* pose_in = (const float*)d_in[0];
    const float* act_in  = (const float*)d_in[1];
    const float* wmat    = (const float*)d_in[2];
    const float* beta_v  = (const float*)d_in[3];
    const float* beta_a  = (const float*)d_in[4];
    float* out = (float*)d_out;

    float* bufA    = (float*)d_ws;                              // 10.0 MB
    float* bufB    = bufA + (size_t)NPOS * SUBS * CHUNK;        // 10.0 MB
    float* statbuf = bufB + (size_t)NPOS * SUBS * CHUNK;        // 2.65 MB

    dim3 block(256);
    dim3 gridS(144 * SUBS);    // 576 = 144 yx * 4 sub
    dim3 gridN(NPOS);          // 576 positions

    sweep_kernel<0><<<gridS, block, 0, stream>>>(pose_in, act_in, wmat, nullptr, bufA);
    stats_kernel<1><<<gridN, block, 0, stream>>>(bufA, beta_v, beta_a, statbuf);
    sweep_kernel<1><<<gridS, block, 0, stream>>>(pose_in, act_in, wmat, statbuf, bufB);
    stats_kernel<2><<<gridN, block, 0, stream>>>(bufB, beta_v, beta_a, statbuf);
    sweep_kernel<2><<<gridS, block, 0, stream>>>(pose_in, act_in, wmat, statbuf, bufA);
    final_kernel<<<gridN, block, 0, stream>>>(bufA, beta_v, beta_a, out);
}

// Round 12
// 130.224 us; speedup vs baseline: 1.4717x; 1.4717x over previous
//
#include <hip/hip_runtime.h>
#include <math.h>

namespace {

constexpr int SOUT = 12;    // (14-3)/1+1
constexpr int OCAP = 32;
constexpr int PD   = 16;    // 4x4 pose
constexpr int NI   = 288;   // 3*3*32
constexpr int SUBS = 4;     // i-dimension split factor
constexpr int ISUB = NI / SUBS;        // 72 input caps per (block,sub)
constexpr int NPOS = 4 * SOUT * SOUT;  // 576 output positions
constexpr float EPSF = 1e-9f;
constexpr int CHUNK = 34 * 32;         // per-(n,sub) partial: [o][34]; 0..15 S1, 16..31 S2, 32 S0
constexpr int SSTR  = 36;              // stat row stride per o: 16 i2, 16 ng, bias, pad
constexpr size_t POSE_OUT = (size_t)NPOS * OCAP * PD;  // 294912

typedef float v2f __attribute__((ext_vector_type(2)));

__device__ __forceinline__ v2f vfma(v2f a, v2f b, v2f c) { return __builtin_elementwise_fma(a, b, c); }
__device__ __forceinline__ v2f splat(float a) { v2f r; r.x = a; r.y = a; return r; }

// DPP lane exchange (compile-time ctrl); folds into v_max_f32_dpp / v_add_f32_dpp.
// All four levels stay within a 16-lane DPP row -> reduction is per 16-lane group.
template<int CTRL>
__device__ __forceinline__ float dppf(float x) {
    return __int_as_float(__builtin_amdgcn_update_dpp(0, __float_as_int(x), CTRL, 0xF, 0xF, true));
}
__device__ __forceinline__ float redmax16(float x) {
    x = fmaxf(x, dppf<0xB1>(x));    // quad_perm xor1
    x = fmaxf(x, dppf<0x4E>(x));    // quad_perm xor2
    x = fmaxf(x, dppf<0x141>(x));   // row_half_mirror (xor4)
    x = fmaxf(x, dppf<0x140>(x));   // row_mirror (xor8)
    return x;
}
__device__ __forceinline__ float redsum16(float x) {
    x += dppf<0xB1>(x);
    x += dppf<0x4E>(x);
    x += dppf<0x141>(x);
    x += dppf<0x140>(x);
    return x;
}

// W row (16 contiguous floats) as 8 packed pairs over r: W2[p-na] see vote8
__device__ __forceinline__ void loadW(const float* __restrict__ p, v2f (&W)[8]) {
    const float4 w0 = *reinterpret_cast<const float4*>(p);
    const float4 w1 = *reinterpret_cast<const float4*>(p + 4);
    const float4 w2 = *reinterpret_cast<const float4*>(p + 8);
    const float4 w3 = *reinterpret_cast<const float4*>(p + 12);
    W[0].x=w0.x; W[0].y=w0.y; W[1].x=w0.z; W[1].y=w0.w;
    W[2].x=w1.x; W[2].y=w1.y; W[3].x=w1.z; W[3].y=w1.w;
    W[4].x=w2.x; W[4].y=w2.y; W[5].x=w2.z; W[5].y=w2.w;
    W[6].x=w3.x; W[6].y=w3.y; W[7].x=w3.z; W[7].y=w3.w;
}

// votes: v[p*2+h] = {votes[p][2h], votes[p][2h+1]} = sum_q P[p][q]*W2[q*2+h]
__device__ __forceinline__ void vote8(const float4 p0, const float4 p1,
                                      const float4 p2, const float4 p3,
                                      const v2f (&W)[8], v2f (&v)[8]) {
    #pragma unroll
    for (int h = 0; h < 2; ++h) {
        v[0 + h] = vfma(splat(p0.x), W[0+h], vfma(splat(p0.y), W[2+h],
                   vfma(splat(p0.z), W[4+h], splat(p0.w) * W[6+h])));
        v[2 + h] = vfma(splat(p1.x), W[0+h], vfma(splat(p1.y), W[2+h],
                   vfma(splat(p1.z), W[4+h], splat(p1.w) * W[6+h])));
        v[4 + h] = vfma(splat(p2.x), W[0+h], vfma(splat(p2.y), W[2+h],
                   vfma(splat(p2.z), W[4+h], splat(p2.w) * W[6+h])));
        v[6 + h] = vfma(splat(p3.x), W[0+h], vfma(splat(p3.y), W[2+h],
                   vfma(splat(p3.z), W[4+h], splat(p3.w) * W[6+h])));
    }
}

// acc-pair h -> pose dim d: d = (h>>1)*4 + (h&1)*2  (components d, d+1)
__device__ __forceinline__ constexpr int DH(int h) { return (h >> 1) * 4 + (h & 1) * 2; }

// ---------------------------------------------------------------------------
// Sweep: block = (yx, sub). 4 waves; wave = batch b (W stream shared via L1).
// Lane = (o16 = lane&15, iq = lane>>4). Per wave-step 4 i (one per 16-lane
// group, SIMT-parallel softmax, pure-DPP reduction). Each lane covers o16 and
// o16+16 (two d-packed vote chains). 18 steps cover the 72-cap chunk.
// ---------------------------------------------------------------------------
template<int SWEEP>
__global__ __launch_bounds__(256, 2)
void sweep_kernel(const float* __restrict__ pose_in,   // [4,14,14,32,16]
                  const float* __restrict__ act_in,    // [4,14,14,32]
                  const float* __restrict__ wmat,      // [288,32,16]
                  const float* __restrict__ statbuf,   // [576][32][36] finalized stats
                  float* __restrict__ outbuf)          // partials [n*4+sub][CHUNK]
{
    __shared__ __align__(16) float sP[4 * ISUB * PD]; // 18.4 KB: 4 batches' i-chunks
    __shared__ float sA[4 * ISUB];

    const int bid = blockIdx.x;
    const int yx  = bid >> 2;
    const int sub = bid & 3;
    const int y   = yx / SOUT;
    const int x   = yx % SOUT;

    const int t    = threadIdx.x;
    const int wave = t >> 6;            // 0..3 = batch b
    const int lane = t & 63;
    const int o16  = lane & 15;         // low output capsule (also owns o16+16)
    const int iq   = lane >> 4;         // 0..3: i-group within step

    // ---- stage 4 batches' i-chunks (coalesced float4) ----
    {
        const float4* src = reinterpret_cast<const float4*>(pose_in);
        float4* dst = reinterpret_cast<float4*>(sP);
        for (int u = t; u < 4 * ISUB * 4; u += 256) {  // 1152 float4
            const int bs   = u / (ISUB * 4);
            const int r    = u - bs * (ISUB * 4);
            const int il   = r >> 2;
            const int comp = r & 3;
            const int ig   = sub * ISUB + il;
            const int k = ig >> 5, c = ig & 31;
            const int ki = k / 3, kj = k - ki * 3;
            const int cell = (bs * 14 + y + ki) * 14 + (x + kj);
            dst[u] = src[(size_t)(cell * 32 + c) * 4 + comp];
        }
        for (int u = t; u < 4 * ISUB; u += 256) {
            const int bs = u / ISUB;
            const int il = u - bs * ISUB;
            const int ig = sub * ISUB + il;
            const int k = ig >> 5, c = ig & 31;
            const int ki = k / 3, kj = k - ki * 3;
            const int cell = (bs * 14 + y + ki) * 14 + (x + kj);
            sA[u] = act_in[(size_t)cell * 32 + c];
        }
    }

    const int n = wave * (SOUT * SOUT) + yx;

    // per-lane register cache of stats for o16 and o16+16
    float bias_l = 0.f, bias_h = 0.f;
    v2f i2l[8], ngl[8], i2h[8], ngh[8];
    if constexpr (SWEEP > 0) {
        const float* stl = statbuf + ((size_t)n * OCAP + o16) * SSTR;
        const float* sth = stl + 16 * SSTR;
        #pragma unroll
        for (int q = 0; q < 4; ++q) {
            const float4 a = *reinterpret_cast<const float4*>(stl + q * 4);
            i2l[q*2].x = a.x; i2l[q*2].y = a.y; i2l[q*2+1].x = a.z; i2l[q*2+1].y = a.w;
            const float4 g = *reinterpret_cast<const float4*>(stl + 16 + q * 4);
            ngl[q*2].x = g.x; ngl[q*2].y = g.y; ngl[q*2+1].x = g.z; ngl[q*2+1].y = g.w;
            const float4 a2 = *reinterpret_cast<const float4*>(sth + q * 4);
            i2h[q*2].x = a2.x; i2h[q*2].y = a2.y; i2h[q*2+1].x = a2.z; i2h[q*2+1].y = a2.w;
            const float4 g2 = *reinterpret_cast<const float4*>(sth + 16 + q * 4);
            ngh[q*2].x = g2.x; ngh[q*2].y = g2.y; ngh[q*2+1].x = g2.z; ngh[q*2+1].y = g2.w;
        }
        bias_l = stl[32];
        bias_h = sth[32];
    }
    __syncthreads();

    v2f s1l[8], s2l[8], s1h[8], s2h[8];
    float s0l = 0.f, s0h = 0.f;
    #pragma unroll
    for (int h = 0; h < 8; ++h) {
        s1l[h] = splat(0.f); s2l[h] = splat(0.f);
        s1h[h] = splat(0.f); s2h[h] = splat(0.f);
    }

    // lane W rows: i = sub*72 + step*4 + iq; lo row (i*32+o16)*16, hi +256 floats
    const float* wl = wmat + ((size_t)((sub * ISUB + iq) * OCAP) + o16) * PD;
    const float* pb = sP + wave * ISUB * PD;
    const float* ab = sA + wave * ISUB;
    // step stride: 4 i = 4*512 = 2048 floats

    v2f WLA[8], WHA[8], WLB[8], WHB[8];
    loadW(wl, WLA);
    loadW(wl + 256, WHA);

#define STEP(st_, WL, WH, WLn, WHn)                                        \
    {                                                                      \
        if ((st_) < 17) {                                                  \
            loadW(wl + (size_t)((st_) + 1) * 2048, WLn);                   \
            loadW(wl + (size_t)((st_) + 1) * 2048 + 256, WHn);             \
        }                                                                  \
        const int il = (st_) * 4 + iq;                                     \
        const float* pr = pb + il * PD;                                    \
        const float4 p0 = *reinterpret_cast<const float4*>(pr);            \
        const float4 p1 = *reinterpret_cast<const float4*>(pr + 4);        \
        const float4 p2 = *reinterpret_cast<const float4*>(pr + 8);        \
        const float4 p3 = *reinterpret_cast<const float4*>(pr + 12);       \
        v2f vl[8], vh[8];                                                  \
        vote8(p0, p1, p2, p3, WL, vl);                                     \
        vote8(p0, p1, p2, p3, WH, vh);                                     \
        const float a_i = ab[il];                                          \
        float rrl, rrh;                                                    \
        if constexpr (SWEEP == 0) {                                        \
            rrl = a_i * (1.0f / 32.0f);                                    \
            rrh = rrl;                                                     \
        } else {                                                           \
            v2f tl2 = splat(0.f), th2 = splat(0.f);                        \
            _Pragma("unroll")                                              \
            for (int h = 0; h < 8; ++h) {                                  \
                tl2 = vfma(vl[h], vfma(vl[h], i2l[h], ngl[h]), tl2);       \
                th2 = vfma(vh[h], vfma(vh[h], i2h[h], ngh[h]), th2);       \
            }                                                              \
            const float zl = bias_l - (tl2.x + tl2.y);                     \
            const float zh = bias_h - (th2.x + th2.y);                     \
            const float m = redmax16(fmaxf(zl, zh));                       \
            const float el = __expf(zl - m);                               \
            const float eh = __expf(zh - m);                               \
            const float es = redsum16(el + eh);                            \
            const float inv = __fdividef(a_i, es);                         \
            rrl = el * inv;                                                \
            rrh = eh * inv;                                                \
        }                                                                  \
        s0l += rrl; s0h += rrh;                                            \
        const v2f r2l = splat(rrl), r2h = splat(rrh);                      \
        _Pragma("unroll")                                                  \
        for (int h = 0; h < 8; ++h) {                                      \
            const v2f rvl = r2l * vl[h];                                   \
            s1l[h] = s1l[h] + rvl;                                         \
            s2l[h] = vfma(rvl, vl[h], s2l[h]);                             \
            const v2f rvh = r2h * vh[h];                                   \
            s1h[h] = s1h[h] + rvh;                                         \
            s2h[h] = vfma(rvh, vh[h], s2h[h]);                             \
        }                                                                  \
    }

    #pragma unroll 1
    for (int kk = 0; kk < 9; ++kk) {
        STEP(2 * kk,     WLA, WHA, WLB, WHB);
        STEP(2 * kk + 1, WLB, WHB, WLA, WHA);
    }
#undef STEP

    // fold the 4 i-groups (lane^16, lane^32)
    #pragma unroll
    for (int h = 0; h < 8; ++h) {
        s1l[h].x += __shfl_xor(s1l[h].x, 16, 64); s1l[h].y += __shfl_xor(s1l[h].y, 16, 64);
        s2l[h].x += __shfl_xor(s2l[h].x, 16, 64); s2l[h].y += __shfl_xor(s2l[h].y, 16, 64);
        s1h[h].x += __shfl_xor(s1h[h].x, 16, 64); s1h[h].y += __shfl_xor(s1h[h].y, 16, 64);
        s2h[h].x += __shfl_xor(s2h[h].x, 16, 64); s2h[h].y += __shfl_xor(s2h[h].y, 16, 64);
    }
    s0l += __shfl_xor(s0l, 16, 64);
    s0h += __shfl_xor(s0h, 16, 64);
    #pragma unroll
    for (int h = 0; h < 8; ++h) {
        s1l[h].x += __shfl_xor(s1l[h].x, 32, 64); s1l[h].y += __shfl_xor(s1l[h].y, 32, 64);
        s2l[h].x += __shfl_xor(s2l[h].x, 32, 64); s2l[h].y += __shfl_xor(s2l[h].y, 32, 64);
        s1h[h].x += __shfl_xor(s1h[h].x, 32, 64); s1h[h].y += __shfl_xor(s1h[h].y, 32, 64);
        s2h[h].x += __shfl_xor(s2h[h].x, 32, 64); s2h[h].y += __shfl_xor(s2h[h].y, 32, 64);
    }
    s0l += __shfl_xor(s0l, 32, 64);
    s0h += __shfl_xor(s0h, 32, 64);

    // lanes 0..15 (iq==0) store both o-rows of the partial chunk
    if (iq == 0) {
        float* base = outbuf + (size_t)(n * SUBS + sub) * CHUNK;
        float* dl = base + o16 * 34;
        float* dh = base + (o16 + 16) * 34;
        #pragma unroll
        for (int h = 0; h < 8; ++h) {
            *reinterpret_cast<float2*>(dl + DH(h))      = float2{s1l[h].x, s1l[h].y};
            *reinterpret_cast<float2*>(dl + 16 + DH(h)) = float2{s2l[h].x, s2l[h].y};
            *reinterpret_cast<float2*>(dh + DH(h))      = float2{s1h[h].x, s1h[h].y};
            *reinterpret_cast<float2*>(dh + 16 + DH(h)) = float2{s2h[h].x, s2h[h].y};
        }
        dl[32] = s0l;
        dh[32] = s0h;
    }
}

// ---------------------------------------------------------------------------
// Stats: finalize iteration stats from the 4 sub-chunks, once per n.
// ---------------------------------------------------------------------------
template<int IT>
__global__ __launch_bounds__(256, 4)
void stats_kernel(const float* __restrict__ prev,
                  const float* __restrict__ beta_v,
                  const float* __restrict__ beta_a,
                  float* __restrict__ statbuf)
{
    const int n  = blockIdx.x;
    const int t  = threadIdx.x;
    const int oo = t >> 3, dp = t & 7, d0 = dp * 2;
    const float* base = prev + (size_t)n * (SUBS * CHUNK) + oo * 34;
    float s0 = 0.f, S1a = 0.f, S1b = 0.f, S2a = 0.f, S2b = 0.f;
    #pragma unroll
    for (int s = 0; s < SUBS; ++s) {
        const float* c = base + s * CHUNK;
        s0  += c[32];
        S1a += c[d0];
        S1b += c[d0 + 1];
        S2a += c[16 + d0];
        S2b += c[17 + d0];
    }
    const float inv = 1.f / s0;
    const float m0 = S1a * inv, m1 = S1b * inv;
    const float v0 = fmaxf(fmaf(-m0, m0, S2a * inv), 0.f);
    const float v1 = fmaxf(fmaf(-m1, m1, S2b * inv), 0.f);
    const float i20 = 0.5f / fmaxf(v0, 1e-30f);
    const float i21 = 0.5f / fmaxf(v1, 1e-30f);
    float ll = __logf(sqrtf(v0) + EPSF) + __logf(sqrtf(v1) + EPSF);
    float c0 = m0 * m0 * i20 + m1 * m1 * i21;

    float* st = statbuf + ((size_t)n * OCAP + oo) * SSTR;
    st[d0]          = i20;
    st[d0 + 1]      = i21;
    st[16 + d0]     = -2.f * m0 * i20;
    st[17 + d0]     = -2.f * m1 * i21;

    #pragma unroll
    for (int m = 1; m <= 4; m <<= 1) {
        ll += __shfl_xor(ll, m, 8);
        c0 += __shfl_xor(c0, m, 8);
    }
    if (dp == 0) {
        const float cost = s0 * fmaf(16.f, beta_v[oo], ll);
        const float oact = 1.f / (1.f + __expf(-(float)IT * (beta_a[oo] - cost)));
        st[32] = __logf(oact + EPSF) - ll - c0;
    }
}

__global__ __launch_bounds__(256, 4)
void final_kernel(const float* __restrict__ prev,      // partials of sweep 2
                  const float* __restrict__ beta_v,
                  const float* __restrict__ beta_a,
                  float* __restrict__ out)
{
    const int n  = blockIdx.x;
    const int t  = threadIdx.x;
    const int oo = t >> 3, dp = t & 7, d0 = dp * 2;
    const float* base = prev + (size_t)n * (SUBS * CHUNK) + oo * 34;
    float s0 = 0.f, S1a = 0.f, S1b = 0.f, S2a = 0.f, S2b = 0.f;
    #pragma unroll
    for (int s = 0; s < SUBS; ++s) {
        const float* c = base + s * CHUNK;
        s0  += c[32];
        S1a += c[d0];
        S1b += c[d0 + 1];
        S2a += c[16 + d0];
        S2b += c[17 + d0];
    }
    const float inv = 1.f / s0;
    const float m0 = S1a * inv, m1 = S1b * inv;
    out[(size_t)n * (OCAP * PD) + oo * PD + d0]     = m0;
    out[(size_t)n * (OCAP * PD) + oo * PD + d0 + 1] = m1;

    const float v0 = fmaxf(fmaf(-m0, m0, S2a * inv), 0.f);
    const float v1 = fmaxf(fmaf(-m1, m1, S2b * inv), 0.f);
    float lt = __logf(sqrtf(v0) + EPSF) + __logf(sqrtf(v1) + EPSF);
    lt += __shfl_xor(lt, 1, 8);
    lt += __shfl_xor(lt, 2, 8);
    lt += __shfl_xor(lt, 4, 8);
    if (dp == 0) {
        const float cost = s0 * fmaf(16.f, beta_v[oo], lt);
        const float oact = 1.f / (1.f + __expf(-3.0f * (beta_a[oo] - cost)));  // inv_temp=3 at it=2
        out[POSE_OUT + (size_t)n * OCAP + oo] = oact;
    }
}

} // namespace

extern "C" void kernel_launch(void* const* d_in, const int* in_sizes, int n_in,
                              void* d_out, int out_size, void* d_ws, size_t ws_size,
                              hipStream_t stream) {
    const float* pose_in = (const float*)d_in[0];
    const float* act_in  = (const float*)d_in[1];
    const float* wmat    = (const float*)d_in[2];
    const float* beta_v  = (const float*)d_in[3];
    const float* beta_a  = (const float*)d_in[4];
    float* out = (float*)d_out;

    float* bufA    = (float*)d_ws;                              // 10.0 MB
    float* bufB    = bufA + (size_t)NPOS * SUBS * CHUNK;        // 10.0 MB
    float* statbuf = bufB + (size_t)NPOS * SUBS * CHUNK;        // 2.65 MB

    dim3 block(256);
    dim3 gridS(144 * SUBS);    // 576 = 144 yx * 4 sub
    dim3 gridN(NPOS);          // 576 positions

    sweep_kernel<0><<<gridS, block, 0, stream>>>(pose_in, act_in, wmat, nullptr, bufA);
    stats_kernel<1><<<gridN, block, 0, stream>>>(bufA, beta_v, beta_a, statbuf);
    sweep_kernel<1><<<gridS, block, 0, stream>>>(pose_in, act_in, wmat, statbuf, bufB);
    stats_kernel<2><<<gridN, block, 0, stream>>>(bufB, beta_v, beta_a, statbuf);
    sweep_kernel<2><<<gridS, block, 0, stream>>>(pose_in, act_in, wmat, statbuf, bufA);
    final_kernel<<<gridN, block, 0, stream>>>(bufA, beta_v, beta_a, out);
}

// Round 13
// 116.015 us; speedup vs baseline: 1.6519x; 1.1225x over previous
//
#include <hip/hip_runtime.h>
#include <math.h>

namespace {

constexpr int SOUT = 12;    // (14-3)/1+1
constexpr int OCAP = 32;
constexpr int PD   = 16;    // 4x4 pose
constexpr int NI   = 288;   // 3*3*32
constexpr int SUBS = 4;     // i-dimension split factor
constexpr int ISUB = NI / SUBS;        // 72 input caps per block
constexpr int NPOS = 4 * SOUT * SOUT;  // 576 output positions
constexpr float EPSF = 1e-9f;
constexpr int CHUNK = 33 * 32;         // per-(n,sub) partial: j*32+o ; j 0..15 S1, 16..31 S2, 32 S0
constexpr size_t POSE_OUT = (size_t)NPOS * OCAP * PD;  // 294912

typedef float v2f __attribute__((ext_vector_type(2)));

__device__ __forceinline__ v2f vfma(v2f a, v2f b, v2f c) { return __builtin_elementwise_fma(a, b, c); }
__device__ __forceinline__ v2f splat(float a) { v2f r; r.x = a; r.y = a; return r; }

// DPP lane exchange (compile-time ctrl); folds into v_add_f32_dpp.
template<int CTRL>
__device__ __forceinline__ float dppf(float x) {
    return __int_as_float(__builtin_amdgcn_update_dpp(0, __float_as_int(x), CTRL, 0xF, 0xF, true));
}
// ds_swizzle xor-16 within 32-lane groups (BitMode: offset = (xor<<10) | and=0x1F)
#define SWZ16(x) __int_as_float(__builtin_amdgcn_ds_swizzle(__float_as_int(x), (16 << 10) | 0x1F))

// 32-lane all-reduce sum (4 DPP levels + 1 swizzle)
__device__ __forceinline__ float redsum32(float x) {
    x += dppf<0xB1>(x);
    x += dppf<0x4E>(x);
    x += dppf<0x141>(x);
    x += dppf<0x140>(x);
    x += SWZ16(x);
    return x;
}

// W fragment as 8 packed pairs over r: W2[q*2+h] = {W[q][2h], W[q][2h+1]}
__device__ __forceinline__ void loadW(const float* __restrict__ p, v2f (&W)[8]) {
    const float4 w0 = *reinterpret_cast<const float4*>(p);
    const float4 w1 = *reinterpret_cast<const float4*>(p + 4);
    const float4 w2 = *reinterpret_cast<const float4*>(p + 8);
    const float4 w3 = *reinterpret_cast<const float4*>(p + 12);
    W[0].x=w0.x; W[0].y=w0.y; W[1].x=w0.z; W[1].y=w0.w;
    W[2].x=w1.x; W[2].y=w1.y; W[3].x=w1.z; W[3].y=w1.w;
    W[4].x=w2.x; W[4].y=w2.y; W[5].x=w2.z; W[5].y=w2.w;
    W[6].x=w3.x; W[6].y=w3.y; W[7].x=w3.z; W[7].y=w3.w;
}

// votes: v[p*2+h] = {votes[p][2h], votes[p][2h+1]} = sum_q P[p][q]*W2[q*2+h]
__device__ __forceinline__ void vote8(const float* __restrict__ pr, const v2f (&W)[8], v2f (&v)[8]) {
    #pragma unroll
    for (int p = 0; p < 4; ++p) {
        const float4 pv = *reinterpret_cast<const float4*>(pr + p * 4);
        #pragma unroll
        for (int h = 0; h < 2; ++h) {
            v2f acc = splat(pv.w) * W[6 + h];
            acc = vfma(splat(pv.z), W[4 + h], acc);
            acc = vfma(splat(pv.y), W[2 + h], acc);
            acc = vfma(splat(pv.x), W[0 + h], acc);
            v[p * 2 + h] = acc;
        }
    }
}

// acc-pair h -> pose dim d: d = (h>>1)*4 + (h&1)*2  (components d, d+1)
__device__ __forceinline__ constexpr int DH(int h) { return (h >> 1) * 4 + (h & 1) * 2; }

// One block = (position n, i-quarter sub). 256 threads = 4 waves.
// slot = t>>5 (0..7) picks the input-capsule lane; o = t&31 the output capsule.
template<int SWEEP>
__global__ __launch_bounds__(256, 2)
void sweep_kernel(const float* __restrict__ pose_in,   // [4,14,14,32,16]
                  const float* __restrict__ act_in,    // [4,14,14,32]
                  const float* __restrict__ wmat,      // [288,32,16]
                  const float* __restrict__ beta_v,    // [32]
                  const float* __restrict__ beta_a,    // [32]
                  const float* __restrict__ prev,      // partials of sweep-1 (unused if SWEEP==0)
                  float* __restrict__ outbuf)          // partials of this sweep
{
    __shared__ __align__(16) float sP[ISUB * PD];     // 4.6 KB quarter-patch poses
    __shared__ float sA[ISUB];
    __shared__ __align__(8) float sStat[OCAP][2 * PD + 2];  // [o][0..15]=i2, [o][16..31]=ng
    __shared__ float sBias[OCAP];                     // log(oact+EPS) - lt - C0
    __shared__ float sRed[2][33][33];                 // two-phase cross-wave partials (8.7 KB)

    const int bid = blockIdx.x;
    const int n   = bid >> 2;
    const int sub = bid & 3;
    const int b   = n / (SOUT * SOUT);
    const int yx  = n % (SOUT * SOUT);
    const int y   = yx / SOUT;
    const int x   = yx % SOUT;

    const int t    = threadIdx.x;
    const int wave = t >> 6;            // 0..3
    const int o    = t & 31;
    const int slot = t >> 5;            // 0..7
    const int half = slot & 1;

    // ---- stage the 72-cap quarter of P and A into LDS (coalesced float4) ----
    {
        const float4* src = reinterpret_cast<const float4*>(pose_in);
        float4* dst = reinterpret_cast<float4*>(sP);
        for (int u = t; u < ISUB * 4; u += 256) {     // 288 float4
            const int il = u >> 2;
            const int i  = sub * ISUB + il;
            const int k = i >> 5, c = i & 31;
            const int ki = k / 3, kj = k - ki * 3;
            const int cell = (b * 14 + y + ki) * 14 + (x + kj);
            dst[u] = src[(size_t)(cell * 32 + c) * 4 + (u & 3)];
        }
        if (t < ISUB) {
            const int i = sub * ISUB + t;
            const int k = i >> 5, c = i & 31;
            const int ki = k / 3, kj = k - ki * 3;
            const int cell = (b * 14 + y + ki) * 14 + (x + kj);
            sA[t] = act_in[(size_t)cell * 32 + c];
        }
    }

    if constexpr (SWEEP > 0) {
        // redundantly finalize previous iteration's stats from the 4 sub-chunks
        const int oo = t >> 3, dp = t & 7, d0 = dp * 2;
        const float* base = prev + (size_t)n * (SUBS * CHUNK);
        float s0 = 0.f, S1a = 0.f, S1b = 0.f, S2a = 0.f, S2b = 0.f;
        #pragma unroll
        for (int s = 0; s < SUBS; ++s) {
            const float* c = base + s * CHUNK;
            s0  += c[32 * 32 + oo];
            S1a += c[(d0)      * 32 + oo];
            S1b += c[(d0 + 1)  * 32 + oo];
            S2a += c[(16 + d0) * 32 + oo];
            S2b += c[(17 + d0) * 32 + oo];
        }
        const float inv = 1.f / s0;
        const float m0 = S1a * inv, m1 = S1b * inv;
        const float v0 = fmaxf(fmaf(-m0, m0, S2a * inv), 0.f);
        const float v1 = fmaxf(fmaf(-m1, m1, S2b * inv), 0.f);
        const float i20 = 0.5f / fmaxf(v0, 1e-30f);
        const float i21 = 0.5f / fmaxf(v1, 1e-30f);
        float ll = __logf(sqrtf(v0) + EPSF) + __logf(sqrtf(v1) + EPSF);
        float c0 = m0 * m0 * i20 + m1 * m1 * i21;
        sStat[oo][d0]          = i20;
        sStat[oo][d0 + 1]      = i21;
        sStat[oo][16 + d0]     = -2.f * m0 * i20;
        sStat[oo][17 + d0]     = -2.f * m1 * i21;
        #pragma unroll
        for (int m = 1; m <= 4; m <<= 1) {
            ll += __shfl_xor(ll, m, 8);
            c0 += __shfl_xor(c0, m, 8);
        }
        if (dp == 0) {
            const float cost = s0 * fmaf(16.f, beta_v[oo], ll);
            const float oact = 1.f / (1.f + __expf(-(float)SWEEP * (beta_a[oo] - cost)));
            sBias[oo] = __logf(oact + EPSF) - ll - c0;
        }
    }
    __syncthreads();

    // per-sweep register cache of the per-o stats (loop-invariant for this thread)
    float bias_r = 0.f;
    v2f i2r[8], ngr[8];
    if constexpr (SWEEP > 0) {
        bias_r = sBias[o];
        #pragma unroll
        for (int h = 0; h < 8; ++h) {
            i2r[h] = *reinterpret_cast<const v2f*>(&sStat[o][2 * h]);
            ngr[h] = *reinterpret_cast<const v2f*>(&sStat[o][16 + 2 * h]);
        }
    }

    v2f s1[8], s2[8];
    float s0acc = 0.f;
    #pragma unroll
    for (int h = 0; h < 8; ++h) { s1[h] = splat(0.f); s2[h] = splat(0.f); }

    const float* wbase = wmat + ((size_t)(sub * ISUB + slot) * OCAP + o) * PD;
    // per-step stride: 8 i -> 8*32*16 = 4096 floats

    v2f WA[8], WB[8];
    loadW(wbase, WA);

#define STEP(st, Wc, Wn)                                                   \
    {                                                                      \
        if ((st) < 8) loadW(wbase + (size_t)((st) + 1) * 4096, Wn);        \
        const int il = (st) * 8 + slot;                                    \
        v2f v[8];                                                          \
        vote8(&sP[il * PD], Wc, v);                                        \
        const float a_i = sA[il];                                          \
        float rrp;                                                         \
        if constexpr (SWEEP == 0) {                                        \
            rrp = a_i * (1.0f / 32.0f);                                    \
        } else {                                                           \
            v2f ts2 = splat(0.f);                                          \
            _Pragma("unroll")                                              \
            for (int h = 0; h < 8; ++h) {                                  \
                const v2f tmp = vfma(v[h], i2r[h], ngr[h]);                \
                ts2 = vfma(v[h], tmp, ts2);                                \
            }                                                              \
            /* shift-invariant softmax WITHOUT max-sub: zz <= -lt, bounded */ \
            const float zz = bias_r - (ts2.x + ts2.y);                     \
            const float e = __expf(zz);                                    \
            const float es = redsum32(e);                                  \
            rrp = __fdividef(e, es) * a_i;                                 \
        }                                                                  \
        s0acc += rrp;                                                      \
        const v2f rr2 = splat(rrp);                                        \
        _Pragma("unroll")                                                  \
        for (int h = 0; h < 8; ++h) {                                      \
            const v2f rv = rr2 * v[h];                                     \
            s1[h] = s1[h] + rv;                                            \
            s2[h] = vfma(rv, v[h], s2[h]);                                 \
        }                                                                  \
    }

    STEP(0, WA, WB); STEP(1, WB, WA); STEP(2, WA, WB); STEP(3, WB, WA);
    STEP(4, WA, WB); STEP(5, WB, WA); STEP(6, WA, WB); STEP(7, WB, WA);
    STEP(8, WA, WB);
#undef STEP

    // fold the two halves (different i, same o) within each wave
    #pragma unroll
    for (int h = 0; h < 8; ++h) {
        s1[h].x += __shfl_xor(s1[h].x, 32, 64);
        s1[h].y += __shfl_xor(s1[h].y, 32, 64);
        s2[h].x += __shfl_xor(s2[h].x, 32, 64);
        s2[h].y += __shfl_xor(s2[h].y, 32, 64);
    }
    s0acc += __shfl_xor(s0acc, 32, 64);

    // two-phase cross-wave reduction into sRed[2][33][33]
    if (wave < 2 && half == 0) {
        #pragma unroll
        for (int h = 0; h < 8; ++h) {
            sRed[wave][DH(h)][o]          = s1[h].x;
            sRed[wave][DH(h) + 1][o]      = s1[h].y;
            sRed[wave][16 + DH(h)][o]     = s2[h].x;
            sRed[wave][16 + DH(h) + 1][o] = s2[h].y;
        }
        sRed[wave][32][o] = s0acc;
    }
    __syncthreads();
    if (wave >= 2 && half == 0) {
        #pragma unroll
        for (int h = 0; h < 8; ++h) {
            sRed[wave - 2][DH(h)][o]          += s1[h].x;
            sRed[wave - 2][DH(h) + 1][o]      += s1[h].y;
            sRed[wave - 2][16 + DH(h)][o]     += s2[h].x;
            sRed[wave - 2][16 + DH(h) + 1][o] += s2[h].y;
        }
        sRed[wave - 2][32][o] += s0acc;
    }
    __syncthreads();

    // cross-wave reduce + coalesced store of this block's partial chunk
    float* dstc = outbuf + (size_t)bid * CHUNK;
    const int oc = t & 31;
    for (int j = t >> 5; j < 33; j += 8)
        dstc[j * 32 + oc] = sRed[0][j][oc] + sRed[1][j][oc];
}

__global__ __launch_bounds__(256, 4)
void final_kernel(const float* __restrict__ prev,      // partials of sweep 2
                  const float* __restrict__ beta_v,
                  const float* __restrict__ beta_a,
                  float* __restrict__ out)
{
    const int n  = blockIdx.x;
    const int t  = threadIdx.x;
    const int oo = t >> 3, dp = t & 7, d0 = dp * 2;
    const float* base = prev + (size_t)n * (SUBS * CHUNK);
    float s0 = 0.f, S1a = 0.f, S1b = 0.f, S2a = 0.f, S2b = 0.f;
    #pragma unroll
    for (int s = 0; s < SUBS; ++s) {
        const float* c = base + s * CHUNK;
        s0  += c[32 * 32 + oo];
        S1a += c[(d0)      * 32 + oo];
        S1b += c[(d0 + 1)  * 32 + oo];
        S2a += c[(16 + d0) * 32 + oo];
        S2b += c[(17 + d0) * 32 + oo];
    }
    const float inv = 1.f / s0;
    const float m0 = S1a * inv, m1 = S1b * inv;
    out[(size_t)n * (OCAP * PD) + oo * PD + d0]     = m0;
    out[(size_t)n * (OCAP * PD) + oo * PD + d0 + 1] = m1;

    const float v0 = fmaxf(fmaf(-m0, m0, S2a * inv), 0.f);
    const float v1 = fmaxf(fmaf(-m1, m1, S2b * inv), 0.f);
    float lt = __logf(sqrtf(v0) + EPSF) + __logf(sqrtf(v1) + EPSF);
    lt += __shfl_xor(lt, 1, 8);
    lt += __shfl_xor(lt, 2, 8);
    lt += __shfl_xor(lt, 4, 8);
    if (dp == 0) {
        const float cost = s0 * fmaf(16.f, beta_v[oo], lt);
        const float oact = 1.f / (1.f + __expf(-3.0f * (beta_a[oo] - cost)));  // inv_temp=3 at it=2
        out[POSE_OUT + (size_t)n * OCAP + oo] = oact;
    }
}

} // namespace

extern "C" void kernel_launch(void* const* d_in, const int* in_sizes, int n_in,
                              void* d_out, int out_size, void* d_ws, size_t ws_size,
                              hipStream_t stream) {
    const float* pose_in = (const float*)d_in[0];
    const float* act_in  = (const float*)d_in[1];
    const float* wmat    = (const float*)d_in[2];
    const float* beta_v  = (const float*)d_in[3];
    const float* beta_a  = (const float*)d_in[4];
    float* out = (float*)d_out;

    float* bufA = (float*)d_ws;                       // 2304*1056 floats = 9.73 MB
    float* bufB = bufA + (size_t)NPOS * SUBS * CHUNK; // ping-pong

    dim3 block(256);
    dim3 gridS(NPOS);          // 576 = 144 yx ... (n,sub) decomposition: 576*... = 2304? no:
    // NOTE: grid is (n, sub) = 576*4 = 2304 blocks
    dim3 gridSweep(NPOS * SUBS);   // 2304
    dim3 gridF(NPOS);              // 576

    sweep_kernel<0><<<gridSweep, block, 0, stream>>>(pose_in, act_in, wmat, beta_v, beta_a, nullptr, bufA);
    sweep_kernel<1><<<gridSweep, block, 0, stream>>>(pose_in, act_in, wmat, beta_v, beta_a, bufA, bufB);
    sweep_kernel<2><<<gridSweep, block, 0, stream>>>(pose_in, act_in, wmat, beta_v, beta_a, bufB, bufA);
    final_kernel<<<gridF, block, 0, stream>>>(bufA, beta_v, beta_a, out);
}